// Round 4
// baseline (921.507 us; speedup 1.0000x reference)
//
#include <hip/hip_runtime.h>
#include <hip/hip_bf16.h>
#include <vector>
#include <cmath>
#include <cstring>

using bf16 = __hip_bfloat16;

static constexpr int kH = 16, kD = 128, kNB = 1024, kML = 512, kQL = 2048, kDM = 2048;

// ================= host precompute of Gt (input-independent) =================
// Gt[n][l] = (solve(F F^T + 0.5 I, F).T)[256 + l][n],  n in [0,1024), l in [0,512)
static void compute_Gt_host(float* Gt) {
  const int n = kNB;      // 1024 basis fns
  const int P = 2 * kML;  // 1024 positions
  std::vector<double> F((size_t)n * P);
  std::vector<double> A((size_t)n * n);
  std::vector<double> pos(P);
  const double shift = 1.0 / (double)P;
  const double p0 = -0.5 + shift, p1 = 1.5 - shift;
  for (int i = 0; i < P; i++) pos[i] = p0 + (p1 - p0) * (double)i / (double)(P - 1);
  const double c0 = 0.3989422804014327;  // 1/sqrt(2*pi)
  std::vector<int> lo(n), hi(n);
  for (int b = 0; b < n; b++) {
    double mu = (double)(b >> 1) / 511.0;
    double sg = (b & 1) ? 0.01 : 0.005;
    double c = c0 / sg;
    double* Fb = &F[(size_t)b * P];
    for (int i = 0; i < P; i++) {
      double t = (pos[i] - mu) / sg;
      Fb[i] = c * exp(-0.5 * t * t);
    }
    int l = 0; while (l < P - 1 && pos[l] < mu - 14.0 * sg) l++;
    int h = P - 1; while (h > 0 && pos[h] > mu + 14.0 * sg) h--;
    lo[b] = l; hi[b] = h;
  }
  // A = F F^T + 0.5 I  (band-limited dot: skipped products are < 1e-40)
  for (int i = 0; i < n; i++) {
    const double* fi = &F[(size_t)i * P];
    for (int j = 0; j <= i; j++) {
      const double* fj = &F[(size_t)j * P];
      int a = lo[i] > lo[j] ? lo[i] : lo[j];
      int b2 = hi[i] < hi[j] ? hi[i] : hi[j];
      double s = 0.0;
      for (int k2 = a; k2 <= b2; k2++) s += fi[k2] * fj[k2];
      A[(size_t)i * n + j] = s;
      if (i != j) A[(size_t)j * n + i] = s;
    }
    A[(size_t)i * n + i] += 0.5;
  }
  // Cholesky (lower, in place)
  for (int j = 0; j < n; j++) {
    double* Aj = &A[(size_t)j * n];
    double d = Aj[j];
    for (int k2 = 0; k2 < j; k2++) d -= Aj[k2] * Aj[k2];
    d = std::sqrt(d);
    Aj[j] = d;
    double inv = 1.0 / d;
    for (int i = j + 1; i < n; i++) {
      double* Ai = &A[(size_t)i * n];
      double s = Ai[j];
      for (int k2 = 0; k2 < j; k2++) s -= Ai[k2] * Aj[k2];
      Ai[j] = s * inv;
    }
  }
  // forward solve L Y = F (in place, vectorized over the 1024 RHS columns)
  for (int i = 0; i < n; i++) {
    double* yi = &F[(size_t)i * P];
    const double* Ai = &A[(size_t)i * n];
    for (int k2 = 0; k2 < i; k2++) {
      double lik = Ai[k2];
      const double* yk = &F[(size_t)k2 * P];
      for (int t = 0; t < P; t++) yi[t] -= lik * yk[t];
    }
    double inv = 1.0 / Ai[i];
    for (int t = 0; t < P; t++) yi[t] *= inv;
  }
  // back solve L^T X = Y (in place)
  for (int i = n - 1; i >= 0; i--) {
    double* xi = &F[(size_t)i * P];
    for (int k2 = i + 1; k2 < n; k2++) {
      double lki = A[(size_t)k2 * n + i];
      const double* xk = &F[(size_t)k2 * P];
      for (int t = 0; t < P; t++) xi[t] -= lki * xk[t];
    }
    double inv = 1.0 / A[(size_t)i * n + i];
    for (int t = 0; t < P; t++) xi[t] *= inv;
  }
  // extract rows 256..767 of the position axis, transposed
  for (int b = 0; b < n; b++)
    for (int l = 0; l < kML; l++)
      Gt[(size_t)b * kML + l] = (float)F[(size_t)b * P + (kML / 2) + l];
}

namespace {
struct Init {
  float* d_Gt = nullptr;         // device-resident copy (preferred)
  float* h_Gt_pinned = nullptr;  // pinned host fallback
  std::vector<float> h_Gt;       // pageable last resort
  Init() {
    h_Gt.resize((size_t)kNB * kML);
    compute_Gt_host(h_Gt.data());
    const size_t bytes = h_Gt.size() * sizeof(float);
    if (hipMalloc((void**)&d_Gt, bytes) == hipSuccess) {
      if (hipMemcpy(d_Gt, h_Gt.data(), bytes, hipMemcpyHostToDevice) != hipSuccess) {
        hipFree(d_Gt);
        d_Gt = nullptr;
      }
    } else {
      d_Gt = nullptr;
    }
    if (!d_Gt) {
      if (hipHostMalloc((void**)&h_Gt_pinned, bytes, 0) == hipSuccess) {
        std::memcpy(h_Gt_pinned, h_Gt.data(), bytes);
      } else {
        h_Gt_pinned = nullptr;
      }
    }
  }
};
Init g_init;  // runs at dlopen, before any graph capture
}

// ================= dtype detection =================
// Scans q (N(0,1)) as bf16. Genuine bf16 N(0,1) never exceeds 2^25; f32 bits
// misread as bf16 hit huge exponents with p~0.4/element over 4096 elements.
__global__ __launch_bounds__(256) void detect_kernel(const unsigned short* __restrict__ q,
                                                     int* __restrict__ flag) {
  int t = threadIdx.x;
  int bad = 0;
  for (int i = t; i < 4096; i += 256) {
    unsigned short u = q[i];
    int e = (u >> 7) & 0xFF;
    if (e >= 0x98) bad = 1;  // |x| >= 2^25
  }
  __shared__ int s[256];
  s[t] = bad;
  __syncthreads();
  for (int k2 = 128; k2 > 0; k2 >>= 1) {
    if (t < k2) s[t] |= s[t + k2];
    __syncthreads();
  }
  if (t == 0) *flag = s[0];  // 1 => inputs are float32
}

// ================= GEMM (f32 SIMT, runtime-dtype B / C-out) =================
// C[m,n] = sum_k A[m,k] * opB[k,n]; TRANSB: opB[k,n] = B[n*ldb+k].
// CMODE: 1 = f32 workspace C, 2 = runtime-dtype C (flag).
template <bool TRANSB, int CMODE>
__global__ __launch_bounds__(256) void gemm_rt(
    const float* __restrict__ A, int lda,
    const void* __restrict__ B, int ldb,
    void* __restrict__ C, int ldc,
    int M, int N, int K, const int* __restrict__ flag) {
  const bool f32 = (*flag != 0);
  __shared__ float As[16][65];
  __shared__ float Bs[16][65];
  const int m0 = blockIdx.y * 64, n0 = blockIdx.x * 64;
  const int t = threadIdx.x;
  const int tx = t & 15, ty = t >> 4;
  const int am = t >> 2;        // 0..63
  const int ak = (t & 3) * 4;   // 0,4,8,12
  const int bk = t >> 4;        // 0..15
  const int bn = (t & 15) * 4;  // 0..60
  float acc[4][4] = {};
  for (int k0 = 0; k0 < K; k0 += 16) {
    {
      int m = m0 + am;
#pragma unroll
      for (int c = 0; c < 4; c++) {
        As[ak + c][am] = A[(long long)m * lda + k0 + ak + c];
      }
    }
    if (!TRANSB) {
      long long base = (long long)(k0 + bk) * ldb + n0 + bn;
      if (f32) {
        const float* Bp = (const float*)B;
#pragma unroll
        for (int c = 0; c < 4; c++) Bs[bk][bn + c] = Bp[base + c];
      } else {
        const bf16* Bp = (const bf16*)B;
#pragma unroll
        for (int c = 0; c < 4; c++) Bs[bk][bn + c] = __bfloat162float(Bp[base + c]);
      }
    } else {
      long long base = (long long)(n0 + am) * ldb + k0 + ak;
      if (f32) {
        const float* Bp = (const float*)B;
#pragma unroll
        for (int c = 0; c < 4; c++) Bs[ak + c][am] = Bp[base + c];
      } else {
        const bf16* Bp = (const bf16*)B;
#pragma unroll
        for (int c = 0; c < 4; c++) Bs[ak + c][am] = __bfloat162float(Bp[base + c]);
      }
    }
    __syncthreads();
#pragma unroll
    for (int kk = 0; kk < 16; kk++) {
      float a[4], b[4];
#pragma unroll
      for (int i = 0; i < 4; i++) a[i] = As[kk][ty * 4 + i];
#pragma unroll
      for (int j = 0; j < 4; j++) b[j] = Bs[kk][tx * 4 + j];
#pragma unroll
      for (int i = 0; i < 4; i++)
#pragma unroll
        for (int j = 0; j < 4; j++) acc[i][j] += a[i] * b[j];
    }
    __syncthreads();
  }
#pragma unroll
  for (int i = 0; i < 4; i++) {
    long long row = (long long)(m0 + ty * 4 + i) * ldc + n0 + tx * 4;
    if (CMODE == 1) {
      float* Cp = (float*)C;
#pragma unroll
      for (int j = 0; j < 4; j++) Cp[row + j] = acc[i][j];
    } else {
      if (f32) {
        float* Cp = (float*)C;
#pragma unroll
        for (int j = 0; j < 4; j++) Cp[row + j] = acc[i][j];
      } else {
        bf16* Cp = (bf16*)C;
#pragma unroll
        for (int j = 0; j < 4; j++) Cp[row + j] = __float2bfloat16(acc[i][j]);
      }
    }
  }
}

// Fused context GEMM: Ctx[q, h*128+n] = sum_k r(h,q,k) * V[k, h*128+n]
// r generated on the fly from (mu, sigsq) — never materialized.
__global__ __launch_bounds__(256) void ctx_gemm_kernel(
    const float* __restrict__ mu_all, const float* __restrict__ s2_all,
    const float* __restrict__ V,  // 1024 x 2048 f32 (ws)
    float* __restrict__ Ctx) {    // 2048 x 2048 f32 (ws)
  __shared__ float As[16][65];
  __shared__ float Bs[16][65];
  const int h = blockIdx.z;
  const int m0 = blockIdx.y * 64, n0 = blockIdx.x * 64;  // n0 in {0,64}
  const int t = threadIdx.x;
  const int tx = t & 15, ty = t >> 4;
  const int am = t >> 2;        // 0..63
  const int ak = (t & 3) * 4;   // 0,4,8,12
  const int bk = t >> 4;        // 0..15
  const int bn = (t & 15) * 4;  // 0..60
  const int mrow = m0 + am;
  const float mu_m = mu_all[h * kQL + mrow];
  const float s2_m = s2_all[h * kQL + mrow];
  float inv_s[2], coef[2];
  inv_s[0] = rsqrtf(s2_m + 2.5e-5f);  // b_sigma = 0.005 (even n)
  inv_s[1] = rsqrtf(s2_m + 1e-4f);    // b_sigma = 0.01  (odd n)
  coef[0] = 0.3989422804014327f * inv_s[0];
  coef[1] = 0.3989422804014327f * inv_s[1];
  float acc[4][4] = {};
  for (int k0 = 0; k0 < kNB; k0 += 16) {
#pragma unroll
    for (int c = 0; c < 4; c++) {
      int n = k0 + ak + c;
      float bmu = (float)(n >> 1) * (1.f / 511.f);
      float tt = (bmu - mu_m) * inv_s[n & 1];
      As[ak + c][am] = coef[n & 1] * __expf(-0.5f * tt * tt);
    }
    {
      int kk = k0 + bk;
#pragma unroll
      for (int c = 0; c < 4; c++) {
        Bs[bk][bn + c] = V[(long long)kk * kDM + h * kD + n0 + bn + c];
      }
    }
    __syncthreads();
#pragma unroll
    for (int kk = 0; kk < 16; kk++) {
      float a[4], b[4];
#pragma unroll
      for (int i = 0; i < 4; i++) a[i] = As[kk][ty * 4 + i];
#pragma unroll
      for (int j = 0; j < 4; j++) b[j] = Bs[kk][tx * 4 + j];
#pragma unroll
      for (int i = 0; i < 4; i++)
#pragma unroll
        for (int j = 0; j < 4; j++) acc[i][j] += a[i] * b[j];
    }
    __syncthreads();
  }
#pragma unroll
  for (int i = 0; i < 4; i++) {
    int m = m0 + ty * 4 + i;
#pragma unroll
    for (int j = 0; j < 4; j++) {
      Ctx[(long long)m * kDM + h * kD + n0 + tx * 4 + j] = acc[i][j];
    }
  }
}

// bw[j] = sum_n Bm[n,j] * w[n]   (two weights at once; atomic partial sums)
__global__ __launch_bounds__(256) void bw_kernel(const float* __restrict__ Bm,
                                                 const void* __restrict__ wmu,
                                                 const void* __restrict__ wsg,
                                                 float* __restrict__ bw_mu,
                                                 float* __restrict__ bw_sg,
                                                 const int* __restrict__ flag) {
  const bool f32 = (*flag != 0);
  int t = threadIdx.x;
  int j = blockIdx.x * 256 + t;
  int n0 = blockIdx.y * 256;
  __shared__ float swm[256], sws[256];
  if (f32) {
    swm[t] = ((const float*)wmu)[n0 + t];
    sws[t] = ((const float*)wsg)[n0 + t];
  } else {
    swm[t] = __bfloat162float(((const bf16*)wmu)[n0 + t]);
    sws[t] = __bfloat162float(((const bf16*)wsg)[n0 + t]);
  }
  __syncthreads();
  float smu = 0.f, ssg = 0.f;
  for (int n = 0; n < 256; n++) {
    float b = Bm[(long long)(n0 + n) * kDM + j];
    smu += b * swm[n];
    ssg += b * sws[n];
  }
  atomicAdd(&bw_mu[j], smu);
  atomicAdd(&bw_sg[j], ssg);
}

// kw[i] = sum_j Wk[i,j] * bw[j]
__global__ __launch_bounds__(256) void kw_kernel(const void* __restrict__ Wk,
                                                 const float* __restrict__ bw_mu,
                                                 const float* __restrict__ bw_sg,
                                                 float* __restrict__ kw_mu,
                                                 float* __restrict__ kw_sg,
                                                 const int* __restrict__ flag) {
  const bool f32 = (*flag != 0);
  int i = blockIdx.x;
  float smu = 0.f, ssg = 0.f;
  if (f32) {
    const float* row = (const float*)Wk + (long long)i * kDM;
    for (int j = threadIdx.x; j < kDM; j += 256) {
      float w = row[j];
      smu += w * bw_mu[j];
      ssg += w * bw_sg[j];
    }
  } else {
    const bf16* row = (const bf16*)Wk + (long long)i * kDM;
    for (int j = threadIdx.x; j < kDM; j += 256) {
      float w = __bfloat162float(row[j]);
      smu += w * bw_mu[j];
      ssg += w * bw_sg[j];
    }
  }
  __shared__ float red[2][256];
  red[0][threadIdx.x] = smu;
  red[1][threadIdx.x] = ssg;
  __syncthreads();
  for (int s = 128; s > 0; s >>= 1) {
    if (threadIdx.x < (unsigned)s) {
      red[0][threadIdx.x] += red[0][threadIdx.x + s];
      red[1][threadIdx.x] += red[1][threadIdx.x + s];
    }
    __syncthreads();
  }
  if (threadIdx.x == 0) { kw_mu[i] = red[0][0]; kw_sg[i] = red[1][0]; }
}

// mu[h,q] = sigmoid((q/sqrt(D)) . kw_mu[h]);  sigsq = max(softplus(. kw_sg), 1e-4)
__global__ __launch_bounds__(256) void musig_kernel(const void* __restrict__ q,
                                                    const float* __restrict__ kw_mu,
                                                    const float* __restrict__ kw_sg,
                                                    float* __restrict__ mu,
                                                    float* __restrict__ sigsq,
                                                    const int* __restrict__ flag) {
  const bool f32 = (*flag != 0);
  int w = threadIdx.x >> 6, lane = threadIdx.x & 63;
  int idx = blockIdx.x * 4 + w;  // h*2048 + q
  int h = idx >> 11;
  const float* kmu = kw_mu + h * kD;
  const float* ksg = kw_sg + h * kD;
  float q0, q1;
  if (f32) {
    const float* qrow = (const float*)q + (long long)idx * kD;
    q0 = qrow[lane];
    q1 = qrow[lane + 64];
  } else {
    const bf16* qrow = (const bf16*)q + (long long)idx * kD;
    q0 = __bfloat162float(qrow[lane]);
    q1 = __bfloat162float(qrow[lane + 64]);
  }
  float a = q0 * kmu[lane] + q1 * kmu[lane + 64];
  float b = q0 * ksg[lane] + q1 * ksg[lane + 64];
  for (int s = 32; s > 0; s >>= 1) {
    a += __shfl_xor(a, s);
    b += __shfl_xor(b, s);
  }
  if (lane == 0) {
    const float inv_sqrt_d = 0.08838834764831845f;  // 1/sqrt(128)
    float zm = a * inv_sqrt_d;
    float zs = b * inv_sqrt_d;
    mu[idx] = 1.f / (1.f + __expf(-zm));
    float sp = (zs > 20.f) ? zs : log1pf(__expf(zs));
    sigsq[idx] = fmaxf(sp, 1e-4f);
  }
}

extern "C" void kernel_launch(void* const* d_in, const int* in_sizes, int n_in,
                              void* d_out, int out_size, void* d_ws, size_t ws_size,
                              hipStream_t stream) {
  (void)in_sizes; (void)n_in; (void)out_size; (void)ws_size;
  const void* kmem = d_in[0];
  const void* q    = d_in[1];
  const void* Wk   = d_in[2];
  const void* Wv   = d_in[3];
  const void* Wo   = d_in[4];
  const void* wmu  = d_in[5];
  const void* wsg  = d_in[6];
  // d_in[7] = new_doc (unused)

  // ---- workspace layout (total ~34.5 MB) ----
  char* ws = (char*)d_ws;
  float* Bm      = (float*)ws;                        // 1024 x 2048 f32 (8 MB)
  float* valuesF = (float*)(ws + ((size_t)8 << 20));  // 1024 x 2048 f32 (8 MB)
  float* context = (float*)(ws + ((size_t)16 << 20)); // 2048 x 2048 f32 (16 MB)
  float* tail   = (float*)(ws + ((size_t)32 << 20));
  float* bw_mu = tail;                 // 2048
  float* bw_sg = bw_mu + kDM;          // 2048
  float* kw_mu = bw_sg + kDM;          // 2048
  float* kw_sg = kw_mu + kDM;          // 2048
  float* mu    = kw_sg + kDM;          // 16*2048
  float* sigsq = mu + kH * kQL;        // 16*2048
  int*   flag  = (int*)(sigsq + kH * kQL);
  float* gfall = (float*)(flag + 16);  // 1024*512 fallback Gt (2 MB)

  const float* GtDev = g_init.d_Gt;
  if (!GtDev) {
    const void* src = g_init.h_Gt_pinned ? (const void*)g_init.h_Gt_pinned
                                         : (const void*)g_init.h_Gt.data();
    hipMemcpyAsync(gfall, src, (size_t)kNB * kML * sizeof(float),
                   hipMemcpyHostToDevice, stream);
    GtDev = gfall;
  }

  // 0) detect input dtype (writes flag in ws; kernels branch on it)
  detect_kernel<<<1, 256, 0, stream>>>((const unsigned short*)q, flag);

  // 1) Bm = Gt(1024x512,f32) @ k(512x2048)  -> (1024x2048,f32)
  gemm_rt<false, 1><<<dim3(kDM / 64, kNB / 64), 256, 0, stream>>>(
      GtDev, kML, kmem, kDM, Bm, kDM, kNB, kDM, kML, flag);

  // 2) bw = Bm^T w  (both weights)
  hipMemsetAsync(bw_mu, 0, 2 * kDM * sizeof(float), stream);
  bw_kernel<<<dim3(kDM / 256, kNB / 256), 256, 0, stream>>>(Bm, wmu, wsg, bw_mu, bw_sg, flag);

  // 3) kw = W_key @ bw
  kw_kernel<<<kDM, 256, 0, stream>>>(Wk, bw_mu, bw_sg, kw_mu, kw_sg, flag);

  // 4) mu / sigsq per (h,q)
  musig_kernel<<<kH * kQL / 4, 256, 0, stream>>>(q, kw_mu, kw_sg, mu, sigsq, flag);

  // 5) valuesF = Bm(1024x2048,f32) @ W_val^T -> (1024x2048,f32)
  gemm_rt<true, 1><<<dim3(kDM / 64, kNB / 64), 256, 0, stream>>>(
      Bm, kDM, Wv, kDM, valuesF, kDM, kNB, kDM, kDM, flag);

  // 6+7) context[:, h*128:] = r(h) @ values(h)   (r generated on the fly)
  ctx_gemm_kernel<<<dim3(kD / 64, kQL / 64, kH), 256, 0, stream>>>(
      mu, sigsq, valuesF, context);

  // 8) out = context(2048x2048,f32) @ W_out^T -> runtime dtype
  gemm_rt<true, 2><<<dim3(kDM / 64, kQL / 64), 256, 0, stream>>>(
      context, kDM, Wo, kDM, d_out, kDM, kQL, kDM, kDM, flag);
}

// Round 6
// 765.250 us; speedup vs baseline: 1.2042x; 1.2042x over previous
//
#include <hip/hip_runtime.h>
#include <hip/hip_bf16.h>
#include <vector>
#include <cmath>
#include <cstring>

using bf16 = __hip_bfloat16;
typedef short s16x8 __attribute__((ext_vector_type(8)));
typedef float f32x4 __attribute__((ext_vector_type(4)));

static constexpr int kH = 16, kD = 128, kNB = 1024, kML = 512, kQL = 2048, kDM = 2048;

// ================= host precompute of Gt (input-independent) =================
// Gt[n][l] = G[l][n] where G = (rows 256..767 of) solve(FF^T+0.5I, F)^T
static void compute_Gt_host(float* Gt) {
  const int n = kNB, P = 2 * kML;
  std::vector<double> F((size_t)n * P), A((size_t)n * n), pos(P);
  const double shift = 1.0 / (double)P;
  const double p0 = -0.5 + shift, p1 = 1.5 - shift;
  for (int i = 0; i < P; i++) pos[i] = p0 + (p1 - p0) * (double)i / (double)(P - 1);
  const double c0 = 0.3989422804014327;
  std::vector<int> lo(n), hi(n);
  for (int b = 0; b < n; b++) {
    double mu = (double)(b >> 1) / 511.0;
    double sg = (b & 1) ? 0.01 : 0.005;
    double c = c0 / sg;
    double* Fb = &F[(size_t)b * P];
    for (int i = 0; i < P; i++) { double t = (pos[i] - mu) / sg; Fb[i] = c * exp(-0.5 * t * t); }
    int l = 0; while (l < P - 1 && pos[l] < mu - 14.0 * sg) l++;
    int h = P - 1; while (h > 0 && pos[h] > mu + 14.0 * sg) h--;
    lo[b] = l; hi[b] = h;
  }
  for (int i = 0; i < n; i++) {
    const double* fi = &F[(size_t)i * P];
    for (int j = 0; j <= i; j++) {
      const double* fj = &F[(size_t)j * P];
      int a = lo[i] > lo[j] ? lo[i] : lo[j];
      int b2 = hi[i] < hi[j] ? hi[i] : hi[j];
      double s = 0.0;
      for (int k2 = a; k2 <= b2; k2++) s += fi[k2] * fj[k2];
      A[(size_t)i * n + j] = s;
      if (i != j) A[(size_t)j * n + i] = s;
    }
    A[(size_t)i * n + i] += 0.5;
  }
  for (int j = 0; j < n; j++) {  // Cholesky
    double* Aj = &A[(size_t)j * n];
    double d = Aj[j];
    for (int k2 = 0; k2 < j; k2++) d -= Aj[k2] * Aj[k2];
    d = std::sqrt(d); Aj[j] = d;
    double inv = 1.0 / d;
    for (int i = j + 1; i < n; i++) {
      double* Ai = &A[(size_t)i * n];
      double s = Ai[j];
      for (int k2 = 0; k2 < j; k2++) s -= Ai[k2] * Aj[k2];
      Ai[j] = s * inv;
    }
  }
  for (int i = 0; i < n; i++) {  // L Y = F
    double* yi = &F[(size_t)i * P];
    const double* Ai = &A[(size_t)i * n];
    for (int k2 = 0; k2 < i; k2++) {
      double lik = Ai[k2];
      const double* yk = &F[(size_t)k2 * P];
      for (int t = 0; t < P; t++) yi[t] -= lik * yk[t];
    }
    double inv = 1.0 / Ai[i];
    for (int t = 0; t < P; t++) yi[t] *= inv;
  }
  for (int i = n - 1; i >= 0; i--) {  // L^T X = Y
    double* xi = &F[(size_t)i * P];
    for (int k2 = i + 1; k2 < n; k2++) {
      double lki = A[(size_t)k2 * n + i];
      const double* xk = &F[(size_t)k2 * P];
      for (int t = 0; t < P; t++) xi[t] -= lki * xk[t];
    }
    double inv = 1.0 / A[(size_t)i * n + i];
    for (int t = 0; t < P; t++) xi[t] *= inv;
  }
  for (int b = 0; b < n; b++)
    for (int l = 0; l < kML; l++)
      Gt[(size_t)b * kML + l] = (float)F[(size_t)b * P + (kML / 2) + l];
}

static unsigned short f2bf_host(float x) {
  unsigned u; std::memcpy(&u, &x, 4);
  unsigned r = (u + 0x7FFFu + ((u >> 16) & 1u)) >> 16;
  return (unsigned short)r;
}
static float bf2f_host(unsigned short b) {
  unsigned u = ((unsigned)b) << 16; float f; std::memcpy(&f, &u, 4); return f;
}

namespace {
struct Init {
  float* d_Gt = nullptr;     // f32 Gt[n][l] (mu/sigma path)
  unsigned short* d_GtTh = nullptr;  // bf16-hi GtT[l][n]  [512][1024]
  unsigned short* d_GtTl = nullptr;  // bf16-lo GtT[l][n]
  float* h_Gt_pinned = nullptr;
  unsigned short* h_GtTh_pinned = nullptr;
  unsigned short* h_GtTl_pinned = nullptr;
  std::vector<float> h_Gt;
  std::vector<unsigned short> h_GtTh, h_GtTl;
  Init() {
    h_Gt.resize((size_t)kNB * kML);
    compute_Gt_host(h_Gt.data());
    h_GtTh.resize(h_Gt.size());
    h_GtTl.resize(h_Gt.size());
    for (int l = 0; l < kML; l++)
      for (int n = 0; n < kNB; n++) {
        float v = h_Gt[(size_t)n * kML + l];
        unsigned short hb = f2bf_host(v);
        float rem = v - bf2f_host(hb);
        h_GtTh[(size_t)l * kNB + n] = hb;
        h_GtTl[(size_t)l * kNB + n] = f2bf_host(rem);
      }
    const size_t fb = h_Gt.size() * 4, bb = h_Gt.size() * 2;
    if (hipMalloc((void**)&d_Gt, fb) == hipSuccess) {
      if (hipMemcpy(d_Gt, h_Gt.data(), fb, hipMemcpyHostToDevice) != hipSuccess) { hipFree(d_Gt); d_Gt = nullptr; }
    }
    if (hipMalloc((void**)&d_GtTh, bb) == hipSuccess) {
      if (hipMemcpy(d_GtTh, h_GtTh.data(), bb, hipMemcpyHostToDevice) != hipSuccess) { hipFree(d_GtTh); d_GtTh = nullptr; }
    }
    if (hipMalloc((void**)&d_GtTl, bb) == hipSuccess) {
      if (hipMemcpy(d_GtTl, h_GtTl.data(), bb, hipMemcpyHostToDevice) != hipSuccess) { hipFree(d_GtTl); d_GtTl = nullptr; }
    }
    if (!d_Gt && hipHostMalloc((void**)&h_Gt_pinned, fb, 0) == hipSuccess)
      std::memcpy(h_Gt_pinned, h_Gt.data(), fb);
    if (!d_GtTh && hipHostMalloc((void**)&h_GtTh_pinned, bb, 0) == hipSuccess)
      std::memcpy(h_GtTh_pinned, h_GtTh.data(), bb);
    if (!d_GtTl && hipHostMalloc((void**)&h_GtTl_pinned, bb, 0) == hipSuccess)
      std::memcpy(h_GtTl_pinned, h_GtTl.data(), bb);
  }
};
Init g_init;
}

// ================= device helpers =================
__device__ inline short f2bf(float x) {
  unsigned u = __float_as_uint(x);
  unsigned r = (u + 0x7FFFu + ((u >> 16) & 1u)) >> 16;
  return (short)r;
}
__device__ inline float bf2f(short b) {
  return __uint_as_float(((unsigned)(unsigned short)b) << 16);
}

// ================= dtype detection =================
__global__ __launch_bounds__(256) void detect_kernel(const unsigned short* __restrict__ q,
                                                     int* __restrict__ flag) {
  int t = threadIdx.x;
  int bad = 0;
  for (int i = t; i < 4096; i += 256) {
    int e = (q[i] >> 7) & 0xFF;
    if (e >= 0x98) bad = 1;
  }
  __shared__ int s[256];
  s[t] = bad; __syncthreads();
  for (int k2 = 128; k2 > 0; k2 >>= 1) { if (t < k2) s[t] |= s[t + k2]; __syncthreads(); }
  if (t == 0) *flag = s[0];  // 1 => float32 inputs
}

// elementwise convert (f32|bf16 in) -> bf16, 4 elems/thread
__global__ __launch_bounds__(256) void conv_bf16(const void* __restrict__ in,
                                                 short* __restrict__ out, int n4,
                                                 const int* __restrict__ flag) {
  int i = blockIdx.x * 256 + threadIdx.x;
  if (i >= n4) return;
  if (*flag) {
    float4 v = ((const float4*)in)[i];
    short4 o; o.x = f2bf(v.x); o.y = f2bf(v.y); o.z = f2bf(v.z); o.w = f2bf(v.w);
    ((short4*)out)[i] = o;
  } else {
    ((short4*)out)[i] = ((const short4*)in)[i];
  }
}

// ===== exact f32 mu/sigma path (well-conditioned: random-weight sums only) =====
__global__ __launch_bounds__(512) void gw_kernel(const float* __restrict__ Gt,
                                                 const void* __restrict__ wmu,
                                                 const void* __restrict__ wsg,
                                                 float* __restrict__ gw,
                                                 const int* __restrict__ flag) {
  const bool f32 = (*flag != 0);
  int l = threadIdx.x;  // 512
  float a = 0.f, b = 0.f;
  for (int n = 0; n < kNB; n++) {
    float g = Gt[(long long)n * kML + l];
    float wm_ = f32 ? ((const float*)wmu)[n] : bf2f(((const short*)wmu)[n]);
    float ws_ = f32 ? ((const float*)wsg)[n] : bf2f(((const short*)wsg)[n]);
    a += g * wm_; b += g * ws_;
  }
  gw[l] = a; gw[kML + l] = b;
}

__global__ __launch_bounds__(256) void bwk_kernel(const void* __restrict__ kin,
                                                  const float* __restrict__ gw,
                                                  float* __restrict__ bw,
                                                  const int* __restrict__ flag) {
  const bool f32 = (*flag != 0);
  int j = blockIdx.x * 256 + threadIdx.x;
  float a = 0.f, b = 0.f;
  for (int l = 0; l < kML; l++) {
    float kv = f32 ? ((const float*)kin)[(long long)l * kDM + j]
                   : bf2f(((const short*)kin)[(long long)l * kDM + j]);
    a += kv * gw[l]; b += kv * gw[kML + l];
  }
  bw[j] = a; bw[kDM + j] = b;
}

__global__ __launch_bounds__(256) void kw_kernel(const void* __restrict__ Wk,
                                                 const float* __restrict__ bw,
                                                 float* __restrict__ kw,
                                                 const int* __restrict__ flag) {
  const bool f32 = (*flag != 0);
  int i = blockIdx.x;
  float smu = 0.f, ssg = 0.f;
  if (f32) {
    const float* row = (const float*)Wk + (long long)i * kDM;
    for (int j = threadIdx.x; j < kDM; j += 256) { float w = row[j]; smu += w * bw[j]; ssg += w * bw[kDM + j]; }
  } else {
    const short* row = (const short*)Wk + (long long)i * kDM;
    for (int j = threadIdx.x; j < kDM; j += 256) { float w = bf2f(row[j]); smu += w * bw[j]; ssg += w * bw[kDM + j]; }
  }
  __shared__ float red[2][256];
  red[0][threadIdx.x] = smu; red[1][threadIdx.x] = ssg;
  __syncthreads();
  for (int s = 128; s > 0; s >>= 1) {
    if (threadIdx.x < (unsigned)s) {
      red[0][threadIdx.x] += red[0][threadIdx.x + s];
      red[1][threadIdx.x] += red[1][threadIdx.x + s];
    }
    __syncthreads();
  }
  if (threadIdx.x == 0) { kw[i] = red[0][0]; kw[kDM + i] = red[1][0]; }
}

__global__ __launch_bounds__(256) void musig_kernel(const void* __restrict__ q,
                                                    const float* __restrict__ kw,
                                                    float* __restrict__ mu,
                                                    float* __restrict__ sigsq,
                                                    const int* __restrict__ flag) {
  const bool f32 = (*flag != 0);
  int w = threadIdx.x >> 6, lane = threadIdx.x & 63;
  int idx = blockIdx.x * 4 + w;  // h*2048 + q
  int h = idx >> 11;
  const float* kmu = kw + h * kD;
  const float* ksg = kw + kDM + h * kD;
  float q0, q1;
  if (f32) {
    const float* qrow = (const float*)q + (long long)idx * kD;
    q0 = qrow[lane]; q1 = qrow[lane + 64];
  } else {
    const short* qrow = (const short*)q + (long long)idx * kD;
    q0 = bf2f(qrow[lane]); q1 = bf2f(qrow[lane + 64]);
  }
  float a = q0 * kmu[lane] + q1 * kmu[lane + 64];
  float b = q0 * ksg[lane] + q1 * ksg[lane + 64];
  for (int s = 32; s > 0; s >>= 1) { a += __shfl_xor(a, s); b += __shfl_xor(b, s); }
  if (lane == 0) {
    const float inv_sqrt_d = 0.08838834764831845f;
    float zm = a * inv_sqrt_d, zs = b * inv_sqrt_d;
    mu[idx] = 1.f / (1.f + __expf(-zm));
    float sp = (zs > 20.f) ? zs : log1pf(__expf(zs));
    sigsq[idx] = fmaxf(sp, 1e-4f);
  }
}

// ===== MFMA GEMM: C[M,N] = A[M,K] @ BT[N,K]^T (bf16 in, f32 acc), z-batched =====
// CSTORE: 0 = bf16 row-major; 1 = bf16 transposed (C^T[n][m], short4); 2 = runtime dtype.
template <int CSTORE>
__global__ __launch_bounds__(256) void mfma_gemm_bt(
    const short* __restrict__ A0, int lda, long long sA,
    const short* __restrict__ BT0, int ldb, long long sB,
    void* __restrict__ C0, int ldc, long long sC,
    int K, const int* __restrict__ flag) {
  __shared__ s16x8 lA[512];  // 8 KB each: 8 subtiles x 64 lane-chunks
  __shared__ s16x8 lB[512];
  const short* A = A0 + (long long)blockIdx.z * sA;
  const short* BT = BT0 + (long long)blockIdx.z * sB;
  const int t = threadIdx.x;
  const int wave = t >> 6, lane = t & 63;
  const int quad = lane >> 4, l16 = lane & 15;
  const int wm = wave >> 1, wn = wave & 1;
  const int m0 = blockIdx.y * 128, n0 = blockIdx.x * 128;
  const int r0 = t >> 2, kc = t & 3;
  f32x4 acc[4][4];
  const f32x4 z = {0.f, 0.f, 0.f, 0.f};
#pragma unroll
  for (int i = 0; i < 4; i++)
#pragma unroll
    for (int j = 0; j < 4; j++) acc[i][j] = z;
  for (int k0 = 0; k0 < K; k0 += 32) {
#pragma unroll
    for (int i = 0; i < 2; i++) {
      int m = r0 + i * 64;
      int cidx = (m >> 4) * 64 + kc * 16 + (m & 15);
      lA[cidx] = *(const s16x8*)(A + (long long)(m0 + m) * lda + k0 + kc * 8);
      lB[cidx] = *(const s16x8*)(BT + (long long)(n0 + m) * ldb + k0 + kc * 8);
    }
    __syncthreads();
    s16x8 af[4], bfr[4];
#pragma unroll
    for (int i = 0; i < 4; i++) af[i] = lA[(wm * 4 + i) * 64 + lane];
#pragma unroll
    for (int j = 0; j < 4; j++) bfr[j] = lB[(wn * 4 + j) * 64 + lane];
#pragma unroll
    for (int i = 0; i < 4; i++)
#pragma unroll
      for (int j = 0; j < 4; j++)
        acc[i][j] = __builtin_amdgcn_mfma_f32_16x16x32_bf16(af[i], bfr[j], acc[i][j], 0, 0, 0);
    __syncthreads();
  }
  // epilogue: C/D layout col=lane&15, row=quad*4+reg
  if (CSTORE == 0) {
    short* Cp = (short*)C0 + (long long)blockIdx.z * sC;
#pragma unroll
    for (int i = 0; i < 4; i++)
#pragma unroll
      for (int j = 0; j < 4; j++) {
        int gn = n0 + (wn * 4 + j) * 16 + l16;
#pragma unroll
        for (int rg = 0; rg < 4; rg++) {
          int gm = m0 + (wm * 4 + i) * 16 + quad * 4 + rg;
          Cp[(long long)gm * ldc + gn] = f2bf(acc[i][j][rg]);
        }
      }
  } else if (CSTORE == 1) {
    short* Cp = (short*)C0 + (long long)blockIdx.z * sC;
#pragma unroll
    for (int i = 0; i < 4; i++)
#pragma unroll
      for (int j = 0; j < 4; j++) {
        int gn = n0 + (wn * 4 + j) * 16 + l16;
        int gm = m0 + (wm * 4 + i) * 16 + quad * 4;
        short4 p; p.x = f2bf(acc[i][j][0]); p.y = f2bf(acc[i][j][1]);
        p.z = f2bf(acc[i][j][2]); p.w = f2bf(acc[i][j][3]);
        *(short4*)(Cp + (long long)gn * ldc + gm) = p;
      }
  } else {
    if (*flag) {
      float* Cp = (float*)C0 + (long long)blockIdx.z * sC;
#pragma unroll
      for (int i = 0; i < 4; i++)
#pragma unroll
        for (int j = 0; j < 4; j++) {
          int gn = n0 + (wn * 4 + j) * 16 + l16;
#pragma unroll
          for (int rg = 0; rg < 4; rg++) {
            int gm = m0 + (wm * 4 + i) * 16 + quad * 4 + rg;
            Cp[(long long)gm * ldc + gn] = acc[i][j][rg];
          }
        }
    } else {
      short* Cp = (short*)C0 + (long long)blockIdx.z * sC;
#pragma unroll
      for (int i = 0; i < 4; i++)
#pragma unroll
        for (int j = 0; j < 4; j++) {
          int gn = n0 + (wn * 4 + j) * 16 + l16;
#pragma unroll
          for (int rg = 0; rg < 4; rg++) {
            int gm = m0 + (wm * 4 + i) * 16 + quad * 4 + rg;
            Cp[(long long)gm * ldc + gn] = f2bf(acc[i][j][rg]);
          }
        }
    }
  }
}

// ===== split-precision TT GEMM: TT[row][l] = sum_n r(row, n) * G[l][n] ==========
// r = rh + rl (bf16 split, generated on the fly); G = Gh + Gl (precomputed).
// TT = rh*Gh + rh*Gl + rl*Gh  (3 MFMAs/step -> ~2^-17 operand precision).
// rows = h_local*2048 + q within a 4-head group; mu/s2 pointers pre-offset.
__global__ __launch_bounds__(256) void mfma_tt(
    const float* __restrict__ mu_all, const float* __restrict__ s2_all,
    const short* __restrict__ Gh, const short* __restrict__ Gl,  // [512][1024]
    short* __restrict__ TT) {                                    // [8192][512]
  __shared__ s16x8 lAh[512], lAl[512], lBh[512], lBl[512];  // 32 KB
  const int t = threadIdx.x;
  const int wave = t >> 6, lane = t & 63;
  const int quad = lane >> 4, l16 = lane & 15;
  const int wm = wave >> 1, wn = wave & 1;
  const int m0 = blockIdx.y * 128, n0 = blockIdx.x * 128;  // m=q-rows, n=l
  const int r0 = t >> 2, kc = t & 3;
  // per-thread row params for the 2 rows this thread stages (m = r0, r0+64)
  float muv[2], ivs[2][2], cof[2][2];
#pragma unroll
  for (int i = 0; i < 2; i++) {
    int row = m0 + r0 + i * 64;
    float m_ = mu_all[row], s2 = s2_all[row];
    ivs[i][0] = rsqrtf(s2 + 2.5e-5f);  // b_sigma = 0.005 (even n)
    ivs[i][1] = rsqrtf(s2 + 1e-4f);    // b_sigma = 0.01  (odd n)
    cof[i][0] = 0.3989422804014327f * ivs[i][0];
    cof[i][1] = 0.3989422804014327f * ivs[i][1];
    muv[i] = m_;
  }
  f32x4 acc[4][4];
  const f32x4 z = {0.f, 0.f, 0.f, 0.f};
#pragma unroll
  for (int i = 0; i < 4; i++)
#pragma unroll
    for (int j = 0; j < 4; j++) acc[i][j] = z;
  for (int k0 = 0; k0 < kNB; k0 += 32) {
#pragma unroll
    for (int i = 0; i < 2; i++) {
      int m = r0 + i * 64;
      int cidx = (m >> 4) * 64 + kc * 16 + (m & 15);
      s16x8 hv, lv;
#pragma unroll
      for (int jj = 0; jj < 8; jj++) {
        int n = k0 + kc * 8 + jj;
        float bmu = (float)(n >> 1) * (1.f / 511.f);
        int p = jj & 1;  // parity of n (k0, kc*8 even)
        float tt = (bmu - muv[i]) * ivs[i][p];
        float v = cof[i][p] * __expf(-0.5f * tt * tt);
        short hb = f2bf(v);
        hv[jj] = hb;
        lv[jj] = f2bf(v - bf2f(hb));
      }
      lAh[cidx] = hv;
      lAl[cidx] = lv;
      lBh[cidx] = *(const s16x8*)(Gh + (long long)(n0 + m) * kNB + k0 + kc * 8);
      lBl[cidx] = *(const s16x8*)(Gl + (long long)(n0 + m) * kNB + k0 + kc * 8);
    }
    __syncthreads();
    s16x8 ah[4], al[4], bh[4], bl[4];
#pragma unroll
    for (int i = 0; i < 4; i++) {
      ah[i] = lAh[(wm * 4 + i) * 64 + lane];
      al[i] = lAl[(wm * 4 + i) * 64 + lane];
    }
#pragma unroll
    for (int j = 0; j < 4; j++) {
      bh[j] = lBh[(wn * 4 + j) * 64 + lane];
      bl[j] = lBl[(wn * 4 + j) * 64 + lane];
    }
#pragma unroll
    for (int i = 0; i < 4; i++)
#pragma unroll
      for (int j = 0; j < 4; j++) {
        acc[i][j] = __builtin_amdgcn_mfma_f32_16x16x32_bf16(ah[i], bh[j], acc[i][j], 0, 0, 0);
        acc[i][j] = __builtin_amdgcn_mfma_f32_16x16x32_bf16(ah[i], bl[j], acc[i][j], 0, 0, 0);
        acc[i][j] = __builtin_amdgcn_mfma_f32_16x16x32_bf16(al[i], bh[j], acc[i][j], 0, 0, 0);
      }
    __syncthreads();
  }
#pragma unroll
  for (int i = 0; i < 4; i++)
#pragma unroll
    for (int j = 0; j < 4; j++) {
      int gn = n0 + (wn * 4 + j) * 16 + l16;
#pragma unroll
      for (int rg = 0; rg < 4; rg++) {
        int gm = m0 + (wm * 4 + i) * 16 + quad * 4 + rg;
        TT[(long long)gm * kML + gn] = f2bf(acc[i][j][rg]);
      }
    }
}

extern "C" void kernel_launch(void* const* d_in, const int* in_sizes, int n_in,
                              void* d_out, int out_size, void* d_ws, size_t ws_size,
                              hipStream_t stream) {
  (void)in_sizes; (void)n_in; (void)out_size; (void)ws_size;
  const void* kmem = d_in[0];
  const void* q    = d_in[1];
  const void* Wk   = d_in[2];
  const void* Wv   = d_in[3];
  const void* Wo   = d_in[4];
  const void* wmu  = d_in[5];
  const void* wsg  = d_in[6];

  // ---- workspace layout (~32.5 MB total) ----
  char* ws = (char*)d_ws;
  short* k_bf  = (short*)ws;                          // [512][2048] bf16, 2 MB
  short* kvT   = (short*)(ws + ((size_t)2 << 20));    // [2048][512] bf16, 2 MB
  short* Wv_bf = (short*)(ws + ((size_t)4 << 20));    // [2048][2048] bf16, 8 MB (dead after kv)
  short* Wo_bf = Wv_bf;                               // overlay AFTER kv GEMM
  short* TTc   = (short*)(ws + ((size_t)12 << 20));   // [8192][512] bf16, 8 MB (per 4-head group)
  short* ctx   = (short*)(ws + ((size_t)20 << 20));   // [2048][2048] bf16, 8 MB
  float* tail  = (float*)(ws + ((size_t)28 << 20));
  float* gw    = tail;                 // 2*512
  float* bw    = gw + 2 * kML;         // 2*2048
  float* kw    = bw + 2 * kDM;         // 2*2048
  float* mu    = kw + 2 * kDM;         // 16*2048
  float* sigsq = mu + kH * kQL;        // 16*2048
  int*   flag  = (int*)(sigsq + kH * kQL);
  float* gfall  = (float*)(ws + ((size_t)28 << 20) + ((size_t)1 << 19));  // 2 MB @28.5
  short* ghfall = (short*)(ws + ((size_t)30 << 20) + ((size_t)1 << 19));  // 1 MB @30.5
  short* glfall = (short*)(ws + ((size_t)31 << 20) + ((size_t)1 << 19));  // 1 MB @31.5

  const float* GtF = g_init.d_Gt;
  if (!GtF) {
    const void* src = g_init.h_Gt_pinned ? (const void*)g_init.h_Gt_pinned
                                         : (const void*)g_init.h_Gt.data();
    hipMemcpyAsync(gfall, src, (size_t)kNB * kML * 4, hipMemcpyHostToDevice, stream);
    GtF = gfall;
  }
  const short* Gh = (const short*)g_init.d_GtTh;
  if (!Gh) {
    const void* src = g_init.h_GtTh_pinned ? (const void*)g_init.h_GtTh_pinned
                                           : (const void*)g_init.h_GtTh.data();
    hipMemcpyAsync(ghfall, src, (size_t)kNB * kML * 2, hipMemcpyHostToDevice, stream);
    Gh = ghfall;
  }
  const short* Gl = (const short*)g_init.d_GtTl;
  if (!Gl) {
    const void* src = g_init.h_GtTl_pinned ? (const void*)g_init.h_GtTl_pinned
                                           : (const void*)g_init.h_GtTl.data();
    hipMemcpyAsync(glfall, src, (size_t)kNB * kML * 2, hipMemcpyHostToDevice, stream);
    Gl = glfall;
  }

  // 0) dtype flag
  detect_kernel<<<1, 256, 0, stream>>>((const unsigned short*)q, flag);

  // prep: k, Wv -> bf16
  conv_bf16<<<(kML * kDM / 4 + 255) / 256, 256, 0, stream>>>(kmem, k_bf, kML * kDM / 4, flag);
  conv_bf16<<<(kDM * kDM / 4 + 255) / 256, 256, 0, stream>>>(Wv, Wv_bf, kDM * kDM / 4, flag);

  // exact f32 mu/sigma path
  gw_kernel<<<1, 512, 0, stream>>>(GtF, wmu, wsg, gw, flag);
  bwk_kernel<<<kDM / 256, 256, 0, stream>>>(kmem, gw, bw, flag);
  kw_kernel<<<kDM, 256, 0, stream>>>(Wk, bw, kw, flag);
  musig_kernel<<<kH * kQL / 4, 256, 0, stream>>>(q, kw, mu, sigsq, flag);

  // kv GEMM: kvT[d][l] = (k @ Wv^T)^T   (M=512 l, N=2048 d, K=2048)
  mfma_gemm_bt<1><<<dim3(kDM / 128, kML / 128, 1), 256, 0, stream>>>(
      k_bf, kDM, 0, Wv_bf, kDM, 0, kvT, kML, 0, kDM, flag);

  // Wo -> bf16 (overlays Wv_bf, dead after kv GEMM)
  conv_bf16<<<(kDM * kDM / 4 + 255) / 256, 256, 0, stream>>>(Wo, Wo_bf, kDM * kDM / 4, flag);

  // per 4-head group: TT (split-precision) then ctx block-columns
  for (int g = 0; g < 4; g++) {
    mfma_tt<<<dim3(kML / 128, 4 * kQL / 128, 1), 256, 0, stream>>>(
        mu + (size_t)g * 4 * kQL, sigsq + (size_t)g * 4 * kQL, Gh, Gl, TTc);
    // ctx[q][h*128+d'] = sum_l TT[h_local*2048+q][l] * kvT[h*128+d'][l]
    mfma_gemm_bt<0><<<dim3(1, kQL / 128, 4), 256, 0, stream>>>(
        TTc, kML, (long long)kQL * kML,
        kvT + (size_t)g * 4 * kD * kML, kML, (long long)kD * kML,
        ctx + (size_t)g * 4 * kD, kDM, (long long)kD,
        kML, flag);
  }

  // out = ctx @ Wo^T  (runtime out dtype)
  mfma_gemm_bt<2><<<dim3(kDM / 128, kQL / 128, 1), 256, 0, stream>>>(
      ctx, kDM, 0, Wo_bf, kDM, 0, d_out, kDM, 0, kDM, flag);
}

// Round 7
// 507.510 us; speedup vs baseline: 1.8157x; 1.5079x over previous
//
#include <hip/hip_runtime.h>
#include <hip/hip_bf16.h>
#include <vector>
#include <cmath>
#include <cstring>

using bf16 = __hip_bfloat16;
typedef short s16x8 __attribute__((ext_vector_type(8)));
typedef float f32x4 __attribute__((ext_vector_type(4)));

static constexpr int kH = 16, kD = 128, kNB = 1024, kML = 512, kQL = 2048, kDM = 2048;

// ================= host precompute of Gt (input-independent) =================
// Gt[n][l] = G[l][n] where G = (rows 256..767 of) solve(FF^T+0.5I, F)^T
static void compute_Gt_host(float* Gt) {
  const int n = kNB, P = 2 * kML;
  std::vector<double> F((size_t)n * P), A((size_t)n * n), pos(P);
  const double shift = 1.0 / (double)P;
  const double p0 = -0.5 + shift, p1 = 1.5 - shift;
  for (int i = 0; i < P; i++) pos[i] = p0 + (p1 - p0) * (double)i / (double)(P - 1);
  const double c0 = 0.3989422804014327;
  std::vector<int> lo(n), hi(n);
  for (int b = 0; b < n; b++) {
    double mu = (double)(b >> 1) / 511.0;
    double sg = (b & 1) ? 0.01 : 0.005;
    double c = c0 / sg;
    double* Fb = &F[(size_t)b * P];
    for (int i = 0; i < P; i++) { double t = (pos[i] - mu) / sg; Fb[i] = c * exp(-0.5 * t * t); }
    int l = 0; while (l < P - 1 && pos[l] < mu - 14.0 * sg) l++;
    int h = P - 1; while (h > 0 && pos[h] > mu + 14.0 * sg) h--;
    lo[b] = l; hi[b] = h;
  }
  for (int i = 0; i < n; i++) {
    const double* fi = &F[(size_t)i * P];
    for (int j = 0; j <= i; j++) {
      const double* fj = &F[(size_t)j * P];
      int a = lo[i] > lo[j] ? lo[i] : lo[j];
      int b2 = hi[i] < hi[j] ? hi[i] : hi[j];
      double s = 0.0;
      for (int k2 = a; k2 <= b2; k2++) s += fi[k2] * fj[k2];
      A[(size_t)i * n + j] = s;
      if (i != j) A[(size_t)j * n + i] = s;
    }
    A[(size_t)i * n + i] += 0.5;
  }
  for (int j = 0; j < n; j++) {  // Cholesky
    double* Aj = &A[(size_t)j * n];
    double d = Aj[j];
    for (int k2 = 0; k2 < j; k2++) d -= Aj[k2] * Aj[k2];
    d = std::sqrt(d); Aj[j] = d;
    double inv = 1.0 / d;
    for (int i = j + 1; i < n; i++) {
      double* Ai = &A[(size_t)i * n];
      double s = Ai[j];
      for (int k2 = 0; k2 < j; k2++) s -= Ai[k2] * Aj[k2];
      Ai[j] = s * inv;
    }
  }
  for (int i = 0; i < n; i++) {  // L Y = F
    double* yi = &F[(size_t)i * P];
    const double* Ai = &A[(size_t)i * n];
    for (int k2 = 0; k2 < i; k2++) {
      double lik = Ai[k2];
      const double* yk = &F[(size_t)k2 * P];
      for (int t = 0; t < P; t++) yi[t] -= lik * yk[t];
    }
    double inv = 1.0 / Ai[i];
    for (int t = 0; t < P; t++) yi[t] *= inv;
  }
  for (int i = n - 1; i >= 0; i--) {  // L^T X = Y
    double* xi = &F[(size_t)i * P];
    for (int k2 = i + 1; k2 < n; k2++) {
      double lki = A[(size_t)k2 * n + i];
      const double* xk = &F[(size_t)k2 * P];
      for (int t = 0; t < P; t++) xi[t] -= lki * xk[t];
    }
    double inv = 1.0 / A[(size_t)i * n + i];
    for (int t = 0; t < P; t++) xi[t] *= inv;
  }
  for (int b = 0; b < n; b++)
    for (int l = 0; l < kML; l++)
      Gt[(size_t)b * kML + l] = (float)F[(size_t)b * P + (kML / 2) + l];
}

static unsigned short f2bf_host(float x) {
  unsigned u; std::memcpy(&u, &x, 4);
  unsigned r = (u + 0x7FFFu + ((u >> 16) & 1u)) >> 16;
  return (unsigned short)r;
}
static float bf2f_host(unsigned short b) {
  unsigned u = ((unsigned)b) << 16; float f; std::memcpy(&f, &u, 4); return f;
}

namespace {
struct Init {
  float* d_GtTf = nullptr;           // f32 GtT[l][n]  [512][1024] (gw path, coalesced)
  unsigned short* d_GtTh = nullptr;  // bf16-hi GtT[l][n]
  unsigned short* d_GtTl = nullptr;  // bf16-lo GtT[l][n]
  float* h_GtTf_pinned = nullptr;
  unsigned short* h_GtTh_pinned = nullptr;
  unsigned short* h_GtTl_pinned = nullptr;
  std::vector<float> h_GtTf;
  std::vector<unsigned short> h_GtTh, h_GtTl;
  Init() {
    std::vector<float> h_Gt((size_t)kNB * kML);
    compute_Gt_host(h_Gt.data());
    h_GtTf.resize(h_Gt.size());
    h_GtTh.resize(h_Gt.size());
    h_GtTl.resize(h_Gt.size());
    for (int l = 0; l < kML; l++)
      for (int n = 0; n < kNB; n++) {
        float v = h_Gt[(size_t)n * kML + l];
        h_GtTf[(size_t)l * kNB + n] = v;
        unsigned short hb = f2bf_host(v);
        h_GtTh[(size_t)l * kNB + n] = hb;
        h_GtTl[(size_t)l * kNB + n] = f2bf_host(v - bf2f_host(hb));
      }
    const size_t fb = h_Gt.size() * 4, bb = h_Gt.size() * 2;
    if (hipMalloc((void**)&d_GtTf, fb) == hipSuccess) {
      if (hipMemcpy(d_GtTf, h_GtTf.data(), fb, hipMemcpyHostToDevice) != hipSuccess) { hipFree(d_GtTf); d_GtTf = nullptr; }
    }
    if (hipMalloc((void**)&d_GtTh, bb) == hipSuccess) {
      if (hipMemcpy(d_GtTh, h_GtTh.data(), bb, hipMemcpyHostToDevice) != hipSuccess) { hipFree(d_GtTh); d_GtTh = nullptr; }
    }
    if (hipMalloc((void**)&d_GtTl, bb) == hipSuccess) {
      if (hipMemcpy(d_GtTl, h_GtTl.data(), bb, hipMemcpyHostToDevice) != hipSuccess) { hipFree(d_GtTl); d_GtTl = nullptr; }
    }
    if (!d_GtTf && hipHostMalloc((void**)&h_GtTf_pinned, fb, 0) == hipSuccess)
      std::memcpy(h_GtTf_pinned, h_GtTf.data(), fb);
    if (!d_GtTh && hipHostMalloc((void**)&h_GtTh_pinned, bb, 0) == hipSuccess)
      std::memcpy(h_GtTh_pinned, h_GtTh.data(), bb);
    if (!d_GtTl && hipHostMalloc((void**)&h_GtTl_pinned, bb, 0) == hipSuccess)
      std::memcpy(h_GtTl_pinned, h_GtTl.data(), bb);
  }
};
Init g_init;
}

// ================= device helpers =================
__device__ inline short f2bf(float x) {
  unsigned u = __float_as_uint(x);
  unsigned r = (u + 0x7FFFu + ((u >> 16) & 1u)) >> 16;
  return (short)r;
}
__device__ inline float bf2f(short b) {
  return __uint_as_float(((unsigned)(unsigned short)b) << 16);
}

// ================= dtype detection =================
__global__ __launch_bounds__(256) void detect_kernel(const unsigned short* __restrict__ q,
                                                     int* __restrict__ flag) {
  int t = threadIdx.x;
  int bad = 0;
  for (int i = t; i < 4096; i += 256) {
    int e = (q[i] >> 7) & 0xFF;
    if (e >= 0x98) bad = 1;
  }
  __shared__ int s[256];
  s[t] = bad; __syncthreads();
  for (int k2 = 128; k2 > 0; k2 >>= 1) { if (t < k2) s[t] |= s[t + k2]; __syncthreads(); }
  if (t == 0) *flag = s[0];  // 1 => float32 inputs
}

// elementwise convert (f32|bf16 in) -> bf16, 4 elems/thread
__global__ __launch_bounds__(256) void conv_bf16(const void* __restrict__ in,
                                                 short* __restrict__ out, int n4,
                                                 const int* __restrict__ flag) {
  int i = blockIdx.x * 256 + threadIdx.x;
  if (i >= n4) return;
  if (*flag) {
    float4 v = ((const float4*)in)[i];
    short4 o; o.x = f2bf(v.x); o.y = f2bf(v.y); o.z = f2bf(v.z); o.w = f2bf(v.w);
    ((short4*)out)[i] = o;
  } else {
    ((short4*)out)[i] = ((const short4*)in)[i];
  }
}

// ===== exact f32 mu/sigma path (well-conditioned: random-weight sums only) =====
// gw[l] = sum_n GtT[l][n] * w[n]  -- one block per l, coalesced row reads
__global__ __launch_bounds__(256) void gw_kernel(const float* __restrict__ GtT,
                                                 const void* __restrict__ wmu,
                                                 const void* __restrict__ wsg,
                                                 float* __restrict__ gw,
                                                 const int* __restrict__ flag) {
  const bool f32 = (*flag != 0);
  const int l = blockIdx.x, t = threadIdx.x;
  const float* row = GtT + (long long)l * kNB;
  float a = 0.f, b = 0.f;
  for (int n = t; n < kNB; n += 256) {
    float g = row[n];
    float wm_ = f32 ? ((const float*)wmu)[n] : bf2f(((const short*)wmu)[n]);
    float ws_ = f32 ? ((const float*)wsg)[n] : bf2f(((const short*)wsg)[n]);
    a += g * wm_; b += g * ws_;
  }
  __shared__ float red[2][256];
  red[0][t] = a; red[1][t] = b;
  __syncthreads();
  for (int s = 128; s > 0; s >>= 1) {
    if (t < s) { red[0][t] += red[0][t + s]; red[1][t] += red[1][t + s]; }
    __syncthreads();
  }
  if (t == 0) { gw[l] = red[0][0]; gw[kML + l] = red[1][0]; }
}

// bw[j] += sum_{l in chunk} k[l][j] * gw[l]  -- grid (j-blocks, l-chunks), atomic combine
__global__ __launch_bounds__(256) void bwk_kernel(const void* __restrict__ kin,
                                                  const float* __restrict__ gw,
                                                  float* __restrict__ bw,
                                                  const int* __restrict__ flag) {
  const bool f32 = (*flag != 0);
  int j = blockIdx.x * 256 + threadIdx.x;
  int l0 = blockIdx.y * 32;
  float a = 0.f, b = 0.f;
  for (int l = l0; l < l0 + 32; l++) {
    float kv = f32 ? ((const float*)kin)[(long long)l * kDM + j]
                   : bf2f(((const short*)kin)[(long long)l * kDM + j]);
    a += kv * gw[l]; b += kv * gw[kML + l];
  }
  atomicAdd(&bw[j], a);
  atomicAdd(&bw[kDM + j], b);
}

__global__ __launch_bounds__(256) void kw_kernel(const void* __restrict__ Wk,
                                                 const float* __restrict__ bw,
                                                 float* __restrict__ kw,
                                                 const int* __restrict__ flag) {
  const bool f32 = (*flag != 0);
  int i = blockIdx.x;
  float smu = 0.f, ssg = 0.f;
  if (f32) {
    const float* row = (const float*)Wk + (long long)i * kDM;
    for (int j = threadIdx.x; j < kDM; j += 256) { float w = row[j]; smu += w * bw[j]; ssg += w * bw[kDM + j]; }
  } else {
    const short* row = (const short*)Wk + (long long)i * kDM;
    for (int j = threadIdx.x; j < kDM; j += 256) { float w = bf2f(row[j]); smu += w * bw[j]; ssg += w * bw[kDM + j]; }
  }
  __shared__ float red[2][256];
  red[0][threadIdx.x] = smu; red[1][threadIdx.x] = ssg;
  __syncthreads();
  for (int s = 128; s > 0; s >>= 1) {
    if (threadIdx.x < (unsigned)s) {
      red[0][threadIdx.x] += red[0][threadIdx.x + s];
      red[1][threadIdx.x] += red[1][threadIdx.x + s];
    }
    __syncthreads();
  }
  if (threadIdx.x == 0) { kw[i] = red[0][0]; kw[kDM + i] = red[1][0]; }
}

__global__ __launch_bounds__(256) void musig_kernel(const void* __restrict__ q,
                                                    const float* __restrict__ kw,
                                                    float* __restrict__ mu,
                                                    float* __restrict__ sigsq,
                                                    const int* __restrict__ flag) {
  const bool f32 = (*flag != 0);
  int w = threadIdx.x >> 6, lane = threadIdx.x & 63;
  int idx = blockIdx.x * 4 + w;  // h*2048 + q
  int h = idx >> 11;
  const float* kmu = kw + h * kD;
  const float* ksg = kw + kDM + h * kD;
  float q0, q1;
  if (f32) {
    const float* qrow = (const float*)q + (long long)idx * kD;
    q0 = qrow[lane]; q1 = qrow[lane + 64];
  } else {
    const short* qrow = (const short*)q + (long long)idx * kD;
    q0 = bf2f(qrow[lane]); q1 = bf2f(qrow[lane + 64]);
  }
  float a = q0 * kmu[lane] + q1 * kmu[lane + 64];
  float b = q0 * ksg[lane] + q1 * ksg[lane + 64];
  for (int s = 32; s > 0; s >>= 1) { a += __shfl_xor(a, s); b += __shfl_xor(b, s); }
  if (lane == 0) {
    const float inv_sqrt_d = 0.08838834764831845f;
    float zm = a * inv_sqrt_d, zs = b * inv_sqrt_d;
    mu[idx] = 1.f / (1.f + __expf(-zm));
    float sp = (zs > 20.f) ? zs : log1pf(__expf(zs));
    sigsq[idx] = fmaxf(sp, 1e-4f);
  }
}

// ===== MFMA GEMM: C[M,N] = A[M,K] @ BT[N,K]^T (bf16 in, f32 acc), z-batched =====
// CSTORE: 0 = bf16 row-major; 1 = bf16 transposed (C^T[n][m], short4); 2 = runtime dtype.
template <int CSTORE>
__global__ __launch_bounds__(256) void mfma_gemm_bt(
    const short* __restrict__ A0, int lda, long long sA,
    const short* __restrict__ BT0, int ldb, long long sB,
    void* __restrict__ C0, int ldc, long long sC,
    int K, const int* __restrict__ flag) {
  __shared__ s16x8 lA[512];  // 8 KB each: 8 subtiles x 64 lane-chunks
  __shared__ s16x8 lB[512];
  const short* A = A0 + (long long)blockIdx.z * sA;
  const short* BT = BT0 + (long long)blockIdx.z * sB;
  const int t = threadIdx.x;
  const int wave = t >> 6, lane = t & 63;
  const int quad = lane >> 4, l16 = lane & 15;
  const int wm = wave >> 1, wn = wave & 1;
  const int m0 = blockIdx.y * 128, n0 = blockIdx.x * 128;
  const int r0 = t >> 2, kc = t & 3;
  f32x4 acc[4][4];
  const f32x4 z = {0.f, 0.f, 0.f, 0.f};
#pragma unroll
  for (int i = 0; i < 4; i++)
#pragma unroll
    for (int j = 0; j < 4; j++) acc[i][j] = z;
  for (int k0 = 0; k0 < K; k0 += 32) {
#pragma unroll
    for (int i = 0; i < 2; i++) {
      int m = r0 + i * 64;
      int cidx = (m >> 4) * 64 + kc * 16 + (m & 15);
      lA[cidx] = *(const s16x8*)(A + (long long)(m0 + m) * lda + k0 + kc * 8);
      lB[cidx] = *(const s16x8*)(BT + (long long)(n0 + m) * ldb + k0 + kc * 8);
    }
    __syncthreads();
    s16x8 af[4], bfr[4];
#pragma unroll
    for (int i = 0; i < 4; i++) af[i] = lA[(wm * 4 + i) * 64 + lane];
#pragma unroll
    for (int j = 0; j < 4; j++) bfr[j] = lB[(wn * 4 + j) * 64 + lane];
#pragma unroll
    for (int i = 0; i < 4; i++)
#pragma unroll
      for (int j = 0; j < 4; j++)
        acc[i][j] = __builtin_amdgcn_mfma_f32_16x16x32_bf16(af[i], bfr[j], acc[i][j], 0, 0, 0);
    __syncthreads();
  }
  // epilogue: C/D layout col=lane&15, row=quad*4+reg
  if (CSTORE == 0) {
    short* Cp = (short*)C0 + (long long)blockIdx.z * sC;
#pragma unroll
    for (int i = 0; i < 4; i++)
#pragma unroll
      for (int j = 0; j < 4; j++) {
        int gn = n0 + (wn * 4 + j) * 16 + l16;
#pragma unroll
        for (int rg = 0; rg < 4; rg++) {
          int gm = m0 + (wm * 4 + i) * 16 + quad * 4 + rg;
          Cp[(long long)gm * ldc + gn] = f2bf(acc[i][j][rg]);
        }
      }
  } else if (CSTORE == 1) {
    short* Cp = (short*)C0 + (long long)blockIdx.z * sC;
#pragma unroll
    for (int i = 0; i < 4; i++)
#pragma unroll
      for (int j = 0; j < 4; j++) {
        int gn = n0 + (wn * 4 + j) * 16 + l16;
        int gm = m0 + (wm * 4 + i) * 16 + quad * 4;
        short4 p; p.x = f2bf(acc[i][j][0]); p.y = f2bf(acc[i][j][1]);
        p.z = f2bf(acc[i][j][2]); p.w = f2bf(acc[i][j][3]);
        *(short4*)(Cp + (long long)gn * ldc + gm) = p;
      }
  } else {
    if (*flag) {
      float* Cp = (float*)C0 + (long long)blockIdx.z * sC;
#pragma unroll
      for (int i = 0; i < 4; i++)
#pragma unroll
        for (int j = 0; j < 4; j++) {
          int gn = n0 + (wn * 4 + j) * 16 + l16;
#pragma unroll
          for (int rg = 0; rg < 4; rg++) {
            int gm = m0 + (wm * 4 + i) * 16 + quad * 4 + rg;
            Cp[(long long)gm * ldc + gn] = acc[i][j][rg];
          }
        }
    } else {
      short* Cp = (short*)C0 + (long long)blockIdx.z * sC;
#pragma unroll
      for (int i = 0; i < 4; i++)
#pragma unroll
        for (int j = 0; j < 4; j++) {
          int gn = n0 + (wn * 4 + j) * 16 + l16;
#pragma unroll
          for (int rg = 0; rg < 4; rg++) {
            int gm = m0 + (wm * 4 + i) * 16 + quad * 4 + rg;
            Cp[(long long)gm * ldc + gn] = f2bf(acc[i][j][rg]);
          }
        }
    }
  }
}

// ===== split-precision TT GEMM: TT[row][l] = sum_n r(row, n) * G[l][n] ==========
// r = rh + rl (bf16 split, on the fly); G = Gh + Gl. TT = rh*Gh + rh*Gl + rl*Gh.
__global__ __launch_bounds__(256) void mfma_tt(
    const float* __restrict__ mu_all, const float* __restrict__ s2_all,
    const short* __restrict__ Gh, const short* __restrict__ Gl,  // [512][1024]
    short* __restrict__ TT) {                                    // [8192][512]
  __shared__ s16x8 lAh[512], lAl[512], lBh[512], lBl[512];  // 32 KB
  const int t = threadIdx.x;
  const int wave = t >> 6, lane = t & 63;
  const int quad = lane >> 4, l16 = lane & 15;
  const int wm = wave >> 1, wn = wave & 1;
  const int m0 = blockIdx.y * 128, n0 = blockIdx.x * 128;  // m=q-rows, n=l
  const int r0 = t >> 2, kc = t & 3;
  float muv[2], ivs[2][2], cof[2][2];
#pragma unroll
  for (int i = 0; i < 2; i++) {
    int row = m0 + r0 + i * 64;
    float m_ = mu_all[row], s2 = s2_all[row];
    ivs[i][0] = rsqrtf(s2 + 2.5e-5f);  // b_sigma = 0.005 (even n)
    ivs[i][1] = rsqrtf(s2 + 1e-4f);    // b_sigma = 0.01  (odd n)
    cof[i][0] = 0.3989422804014327f * ivs[i][0];
    cof[i][1] = 0.3989422804014327f * ivs[i][1];
    muv[i] = m_;
  }
  f32x4 acc[4][4];
  const f32x4 z = {0.f, 0.f, 0.f, 0.f};
#pragma unroll
  for (int i = 0; i < 4; i++)
#pragma unroll
    for (int j = 0; j < 4; j++) acc[i][j] = z;
  for (int k0 = 0; k0 < kNB; k0 += 32) {
#pragma unroll
    for (int i = 0; i < 2; i++) {
      int m = r0 + i * 64;
      int cidx = (m >> 4) * 64 + kc * 16 + (m & 15);
      s16x8 hv, lv;
#pragma unroll
      for (int jj = 0; jj < 8; jj++) {
        int n = k0 + kc * 8 + jj;
        float bmu = (float)(n >> 1) * (1.f / 511.f);
        int p = jj & 1;  // parity of n (k0, kc*8 even)
        float tt = (bmu - muv[i]) * ivs[i][p];
        float v = cof[i][p] * __expf(-0.5f * tt * tt);
        short hb = f2bf(v);
        hv[jj] = hb;
        lv[jj] = f2bf(v - bf2f(hb));
      }
      lAh[cidx] = hv;
      lAl[cidx] = lv;
      lBh[cidx] = *(const s16x8*)(Gh + (long long)(n0 + m) * kNB + k0 + kc * 8);
      lBl[cidx] = *(const s16x8*)(Gl + (long long)(n0 + m) * kNB + k0 + kc * 8);
    }
    __syncthreads();
    s16x8 ah[4], al[4], bh[4], bl[4];
#pragma unroll
    for (int i = 0; i < 4; i++) {
      ah[i] = lAh[(wm * 4 + i) * 64 + lane];
      al[i] = lAl[(wm * 4 + i) * 64 + lane];
    }
#pragma unroll
    for (int j = 0; j < 4; j++) {
      bh[j] = lBh[(wn * 4 + j) * 64 + lane];
      bl[j] = lBl[(wn * 4 + j) * 64 + lane];
    }
#pragma unroll
    for (int i = 0; i < 4; i++)
#pragma unroll
      for (int j = 0; j < 4; j++) {
        acc[i][j] = __builtin_amdgcn_mfma_f32_16x16x32_bf16(ah[i], bh[j], acc[i][j], 0, 0, 0);
        acc[i][j] = __builtin_amdgcn_mfma_f32_16x16x32_bf16(ah[i], bl[j], acc[i][j], 0, 0, 0);
        acc[i][j] = __builtin_amdgcn_mfma_f32_16x16x32_bf16(al[i], bh[j], acc[i][j], 0, 0, 0);
      }
    __syncthreads();
  }
#pragma unroll
  for (int i = 0; i < 4; i++)
#pragma unroll
    for (int j = 0; j < 4; j++) {
      int gn = n0 + (wn * 4 + j) * 16 + l16;
#pragma unroll
      for (int rg = 0; rg < 4; rg++) {
        int gm = m0 + (wm * 4 + i) * 16 + quad * 4 + rg;
        TT[(long long)gm * kML + gn] = f2bf(acc[i][j][rg]);
      }
    }
}

extern "C" void kernel_launch(void* const* d_in, const int* in_sizes, int n_in,
                              void* d_out, int out_size, void* d_ws, size_t ws_size,
                              hipStream_t stream) {
  (void)in_sizes; (void)n_in; (void)out_size; (void)ws_size;
  const void* kmem = d_in[0];
  const void* q    = d_in[1];
  const void* Wk   = d_in[2];
  const void* Wv   = d_in[3];
  const void* Wo   = d_in[4];
  const void* wmu  = d_in[5];
  const void* wsg  = d_in[6];

  // ---- workspace layout (~32.5 MB total) ----
  char* ws = (char*)d_ws;
  short* k_bf  = (short*)ws;                          // [512][2048] bf16, 2 MB
  short* kvT   = (short*)(ws + ((size_t)2 << 20));    // [2048][512] bf16, 2 MB
  short* Wv_bf = (short*)(ws + ((size_t)4 << 20));    // [2048][2048] bf16, 8 MB (dead after kv)
  short* Wo_bf = Wv_bf;                               // overlay AFTER kv GEMM
  short* TTc   = (short*)(ws + ((size_t)12 << 20));   // [8192][512] bf16, 8 MB (per 4-head group)
  short* ctx   = (short*)(ws + ((size_t)20 << 20));   // [2048][2048] bf16, 8 MB
  float* tail  = (float*)(ws + ((size_t)28 << 20));
  float* gw    = tail;                 // 2*512
  float* bw    = gw + 2 * kML;         // 2*2048
  float* kw    = bw + 2 * kDM;         // 2*2048
  float* mu    = kw + 2 * kDM;         // 16*2048
  float* sigsq = mu + kH * kQL;        // 16*2048
  int*   flag  = (int*)(sigsq + kH * kQL);
  float* gtffall = (float*)(ws + ((size_t)28 << 20) + ((size_t)1 << 19));  // 2 MB @28.5
  short* ghfall  = (short*)(ws + ((size_t)30 << 20) + ((size_t)1 << 19));  // 1 MB @30.5
  short* glfall  = (short*)(ws + ((size_t)31 << 20) + ((size_t)1 << 19));  // 1 MB @31.5

  const float* GtTf = g_init.d_GtTf;
  if (!GtTf) {
    const void* src = g_init.h_GtTf_pinned ? (const void*)g_init.h_GtTf_pinned
                                           : (const void*)g_init.h_GtTf.data();
    hipMemcpyAsync(gtffall, src, (size_t)kNB * kML * 4, hipMemcpyHostToDevice, stream);
    GtTf = gtffall;
  }
  const short* Gh = (const short*)g_init.d_GtTh;
  if (!Gh) {
    const void* src = g_init.h_GtTh_pinned ? (const void*)g_init.h_GtTh_pinned
                                           : (const void*)g_init.h_GtTh.data();
    hipMemcpyAsync(ghfall, src, (size_t)kNB * kML * 2, hipMemcpyHostToDevice, stream);
    Gh = ghfall;
  }
  const short* Gl = (const short*)g_init.d_GtTl;
  if (!Gl) {
    const void* src = g_init.h_GtTl_pinned ? (const void*)g_init.h_GtTl_pinned
                                           : (const void*)g_init.h_GtTl.data();
    hipMemcpyAsync(glfall, src, (size_t)kNB * kML * 2, hipMemcpyHostToDevice, stream);
    Gl = glfall;
  }

  // 0) dtype flag
  detect_kernel<<<1, 256, 0, stream>>>((const unsigned short*)q, flag);

  // prep: k, Wv -> bf16
  conv_bf16<<<(kML * kDM / 4 + 255) / 256, 256, 0, stream>>>(kmem, k_bf, kML * kDM / 4, flag);
  conv_bf16<<<(kDM * kDM / 4 + 255) / 256, 256, 0, stream>>>(Wv, Wv_bf, kDM * kDM / 4, flag);

  // exact f32 mu/sigma path (parallelized: 512-block gw, 128-block bwk)
  gw_kernel<<<kML, 256, 0, stream>>>(GtTf, wmu, wsg, gw, flag);
  hipMemsetAsync(bw, 0, 2 * kDM * sizeof(float), stream);
  bwk_kernel<<<dim3(kDM / 256, kML / 32), 256, 0, stream>>>(kmem, gw, bw, flag);
  kw_kernel<<<kDM, 256, 0, stream>>>(Wk, bw, kw, flag);
  musig_kernel<<<kH * kQL / 4, 256, 0, stream>>>(q, kw, mu, sigsq, flag);

  // kv GEMM: kvT[d][l] = (k @ Wv^T)^T   (M=512 l, N=2048 d, K=2048)
  mfma_gemm_bt<1><<<dim3(kDM / 128, kML / 128, 1), 256, 0, stream>>>(
      k_bf, kDM, 0, Wv_bf, kDM, 0, kvT, kML, 0, kDM, flag);

  // Wo -> bf16 (overlays Wv_bf, dead after kv GEMM)
  conv_bf16<<<(kDM * kDM / 4 + 255) / 256, 256, 0, stream>>>(Wo, Wo_bf, kDM * kDM / 4, flag);

  // per 4-head group: TT (split-precision) then ctx block-columns
  for (int g = 0; g < 4; g++) {
    mfma_tt<<<dim3(kML / 128, 4 * kQL / 128, 1), 256, 0, stream>>>(
        mu + (size_t)g * 4 * kQL, sigsq + (size_t)g * 4 * kQL, Gh, Gl, TTc);
    // ctx[q][h*128+d'] = sum_l TT[h_local*2048+q][l] * kvT[h*128+d'][l]
    mfma_gemm_bt<0><<<dim3(1, kQL / 128, 4), 256, 0, stream>>>(
        TTc, kML, (long long)kQL * kML,
        kvT + (size_t)g * 4 * kD * kML, kML, (long long)kD * kML,
        ctx + (size_t)g * 4 * kD, kDM, (long long)kD,
        kML, flag);
  }

  // out = ctx @ Wo^T  (runtime out dtype)
  mfma_gemm_bt<2><<<dim3(kDM / 128, kQL / 128, 1), 256, 0, stream>>>(
      ctx, kDM, 0, Wo_bf, kDM, 0, d_out, kDM, 0, kDM, flag);
}